// Round 3
// baseline (126.565 us; speedup 1.0000x reference)
//
#include <hip/hip_runtime.h>

// SNN excitatory layer only (inhibitory layer never affects the returned
// spikes — the scan discards its carry).
//
// R2 changes vs R1:
//  - x_t staged in LDS per block (double-buffered): block cooperatively loads
//    8 KB once, all 4 waves read fragments from LDS. Cuts L2 broadcast
//    traffic 4x (16 MB/step -> 4 MB/step chip-wide).
//  - T14 async-split staging: global loads for x_{t+1} issued at step TOP
//    into registers, ds_write + single barrier at step BOTTOM -> HBM/L2
//    latency hides under the step's compute instead of serializing ahead
//    of the dot product.
//  - identical arithmetic/summation order to R1 -> bit-exact spikes.

constexpr int T_STEPS = 128;
constexpr int N_IN    = 2048;
constexpr int N_EXC   = 2048;
constexpr int WAVES_PER_BLOCK = 4;

// t_pre[t][j]: trace AFTER the step-t update (what stdp_step's dw uses).
__global__ __launch_bounds__(256)
void tp_precompute_kernel(const float* __restrict__ x, float* __restrict__ tp_ws) {
    const int j = blockIdx.x * blockDim.x + threadIdx.x;
    float tp = 0.f;
    #pragma unroll 4
    for (int t = 0; t < T_STEPS; ++t) {
        tp = fmaf(0.05f, x[t * N_IN + j] - tp, tp);
        tp_ws[t * N_IN + j] = tp;
    }
}

__global__ __launch_bounds__(64 * WAVES_PER_BLOCK, 2)
void snn_exc_kernel(const float* __restrict__ x,     // [T, N_IN]
                    const float* __restrict__ w0,    // [N_EXC, N_IN]
                    const float* __restrict__ tp_ws, // [T, N_IN]
                    float* __restrict__ out)         // [T, N_EXC]
{
    __shared__ __align__(16) float xs[2][N_IN];      // 2 x 8 KB double buffer

    const int tid  = threadIdx.x;
    const int lane = tid & 63;
    const int wid  = tid >> 6;
    const int row  = blockIdx.x * WAVES_PER_BLOCK + wid;

    // lane l owns columns j = m*256 + l*4 + {0..3}, m = 0..7
    float w[32];
    {
        const float4* wrow = reinterpret_cast<const float4*>(w0 + (size_t)row * N_IN);
        #pragma unroll
        for (int m = 0; m < 8; ++m) {
            float4 t4 = wrow[m * 64 + lane];
            w[4*m+0] = t4.x; w[4*m+1] = t4.y; w[4*m+2] = t4.z; w[4*m+3] = t4.w;
        }
    }

    // prologue: stage x_0 into xs[0] (32 B per thread)
    {
        const float4* xv = reinterpret_cast<const float4*>(x);
        float4 a = xv[tid], b = xv[tid + 256];
        float4* dst = reinterpret_cast<float4*>(xs[0]);
        dst[tid] = a; dst[tid + 256] = b;
    }
    __syncthreads();

    const float4* tpp = reinterpret_cast<const float4*>(tp_ws) + lane;

    float v = 0.f, syn = 0.f, rho = 0.f, tpost = 0.f;
    int cur = 0;

    for (int t = 0; t < T_STEPS; ++t) {
        // ---- (1) issue prefetch of x_{t+1} into registers (latency hides
        //          under this step's compute; t=127 re-reads row 127) ----
        const int tn = (t + 1 < T_STEPS) ? (t + 1) : (T_STEPS - 1);
        const float4* xv = reinterpret_cast<const float4*>(x + (size_t)tn * N_IN);
        const float4 pa = xv[tid];
        const float4 pb = xv[tid + 256];

        // ---- (2) read x_t fragments from LDS ----
        float4 xq[8];
        {
            const float4* xl = reinterpret_cast<const float4*>(xs[cur]);
            #pragma unroll
            for (int m = 0; m < 8; ++m) xq[m] = xl[m * 64 + lane];
        }

        // ---- (3) dot product (same tree as R1 -> bit-exact) ----
        float a0 = 0.f, a1 = 0.f, a2 = 0.f, a3 = 0.f;
        #pragma unroll
        for (int m = 0; m < 8; ++m) {
            a0 = fmaf(xq[m].x, w[4*m+0], a0);
            a1 = fmaf(xq[m].y, w[4*m+1], a1);
            a2 = fmaf(xq[m].z, w[4*m+2], a2);
            a3 = fmaf(xq[m].w, w[4*m+3], a3);
        }
        float acc = (a0 + a1) + (a2 + a3);
        #pragma unroll
        for (int off = 32; off >= 1; off >>= 1)
            acc += __shfl_xor(acc, off, 64);

        // ---- (4) LIF with refractory (wave-uniform scalar state) ----
        const float v_dec = fmaf(0.1f, syn - v, v);
        syn = fmaf(0.8f, syn, acc);
        const bool refrac = (rho > 0.f);
        const bool spike  = (v_dec > 1.0f) && !refrac;
        v   = (spike || refrac) ? 0.f : v_dec;
        rho = spike ? 5.0f : fmaxf(rho - (refrac ? 1.f : 0.f), 0.f);
        const float zf = spike ? 1.f : 0.f;
        tpost = fmaf(0.05f, zf - tpost, tpost);
        const float c2 = 1e-3f * tpost;

        // ---- (5) STDP update, fused same-step; wave-uniform branch ----
        if (spike) {
            #pragma unroll
            for (int m = 0; m < 8; ++m) {
                float4 tq = tpp[m * 64];
                w[4*m+0] = fmaxf(fmaf(1e-3f, tq.x, fmaf(-c2, xq[m].x, w[4*m+0])), 0.f);
                w[4*m+1] = fmaxf(fmaf(1e-3f, tq.y, fmaf(-c2, xq[m].y, w[4*m+1])), 0.f);
                w[4*m+2] = fmaxf(fmaf(1e-3f, tq.z, fmaf(-c2, xq[m].z, w[4*m+2])), 0.f);
                w[4*m+3] = fmaxf(fmaf(1e-3f, tq.w, fmaf(-c2, xq[m].w, w[4*m+3])), 0.f);
            }
        } else {
            #pragma unroll
            for (int m = 0; m < 8; ++m) {
                w[4*m+0] = fmaxf(fmaf(-c2, xq[m].x, w[4*m+0]), 0.f);
                w[4*m+1] = fmaxf(fmaf(-c2, xq[m].y, w[4*m+1]), 0.f);
                w[4*m+2] = fmaxf(fmaf(-c2, xq[m].z, w[4*m+2]), 0.f);
                w[4*m+3] = fmaxf(fmaf(-c2, xq[m].w, w[4*m+3]), 0.f);
            }
        }

        // ---- (6) emit spike ----
        if (lane == 0) out[t * N_EXC + row] = zf;

        // ---- (7) write prefetched x_{t+1} to the other buffer; barrier.
        //          (other waves finished reading that buffer at the end of
        //           step t-1's barrier; this barrier publishes it for t+1) --
        {
            float4* dst = reinterpret_cast<float4*>(xs[cur ^ 1]);
            dst[tid] = pa; dst[tid + 256] = pb;
        }
        __syncthreads();
        cur ^= 1;
        tpp += N_IN / 4;
    }
}

extern "C" void kernel_launch(void* const* d_in, const int* in_sizes, int n_in,
                              void* d_out, int out_size, void* d_ws, size_t ws_size,
                              hipStream_t stream) {
    const float* x  = (const float*)d_in[0];   // exc_currents [128, 2048] f32
    const float* w0 = (const float*)d_in[1];   // w_exc [2048, 2048] f32
    // d_in[2] (w_inh) unused: inhibitory layer does not affect the output
    float* out = (float*)d_out;                // spikes [128, 2048] f32

    float* tp_ws = (float*)d_ws;               // 1 MiB, ws_size is ample
    tp_precompute_kernel<<<N_IN / 256, 256, 0, stream>>>(x, tp_ws);

    dim3 grid(N_EXC / WAVES_PER_BLOCK);        // 512 blocks
    dim3 block(64 * WAVES_PER_BLOCK);          // 256 threads = 4 waves
    snn_exc_kernel<<<grid, block, 0, stream>>>(x, w0, tp_ws, out);
}

// Round 4
// 95.166 us; speedup vs baseline: 1.3299x; 1.3299x over previous
//
#include <hip/hip_runtime.h>

// SNN excitatory layer only (inhibitory layer never affects the returned
// spikes — the scan discards its carry).
//
// R3 changes vs R2:
//  - KEY SEMANTIC FACT: in the reference LIF, v_dec uses the OLD synaptic
//    current; inp_t only affects step t+1. So the cross-lane reduce of step t
//    is consumed only by step t+1's scalar syn update -> moved OFF the
//    critical path (restructured: LIF/spike first, dot+STDP, reduce last).
//  - DPP-based wave reduce (row_shr 1/2/4/8 + row_bcast 15/31 + readlane):
//    ~50 cy of VALU latency instead of ~700 cy of dependent ds_swizzle hops.
//  - LDS staging + per-step __syncthreads dropped (R2 proved neutral);
//    x_t ping-pongs between two register buffers via 2-step unroll, with
//    next-step prefetch issued at step top. Waves fully decoupled.

constexpr int T_STEPS = 128;
constexpr int N_IN    = 2048;
constexpr int N_EXC   = 2048;
constexpr int WAVES_PER_BLOCK = 4;

// t_pre[t][j]: trace AFTER the step-t update (what stdp_step's dw uses).
__global__ __launch_bounds__(256)
void tp_precompute_kernel(const float* __restrict__ x, float* __restrict__ tp_ws) {
    const int j = blockIdx.x * blockDim.x + threadIdx.x;
    float tp = 0.f;
    #pragma unroll 4
    for (int t = 0; t < T_STEPS; ++t) {
        tp = fmaf(0.05f, x[t * N_IN + j] - tp, tp);
        tp_ws[t * N_IN + j] = tp;
    }
}

template <int CTRL, int RM>
__device__ __forceinline__ float dpp_add(float x) {
    int t = __builtin_amdgcn_update_dpp(0, __builtin_bit_cast(int, x),
                                        CTRL, RM, 0xF, true);
    return x + __builtin_bit_cast(float, t);
}

// Sum across 64 lanes; returns wave-uniform scalar (via readlane -> SGPR).
__device__ __forceinline__ float wave_sum64(float x) {
    x = dpp_add<0x111, 0xF>(x);   // row_shr:1
    x = dpp_add<0x112, 0xF>(x);   // row_shr:2
    x = dpp_add<0x114, 0xF>(x);   // row_shr:4
    x = dpp_add<0x118, 0xF>(x);   // row_shr:8  -> lane15 of each row = row sum
    x = dpp_add<0x142, 0xA>(x);   // row_bcast:15 -> rows 1,3
    x = dpp_add<0x143, 0xC>(x);   // row_bcast:31 -> rows 2,3; lane 63 = total
    return __builtin_bit_cast(float,
        __builtin_amdgcn_readlane(__builtin_bit_cast(int, x), 63));
}

__global__ __launch_bounds__(64 * WAVES_PER_BLOCK, 2)
void snn_exc_kernel(const float* __restrict__ x,     // [T, N_IN]
                    const float* __restrict__ w0,    // [N_EXC, N_IN]
                    const float* __restrict__ tp_ws, // [T, N_IN]
                    float* __restrict__ out)         // [T, N_EXC]
{
    const int lane = threadIdx.x & 63;
    const int wid  = threadIdx.x >> 6;
    const int row  = blockIdx.x * WAVES_PER_BLOCK + wid;

    // lane l owns columns j = m*256 + l*4 + {0..3}, m = 0..7
    float w[32];
    {
        const float4* wrow = reinterpret_cast<const float4*>(w0 + (size_t)row * N_IN);
        #pragma unroll
        for (int m = 0; m < 8; ++m) {
            float4 t4 = wrow[m * 64 + lane];
            w[4*m+0] = t4.x; w[4*m+1] = t4.y; w[4*m+2] = t4.z; w[4*m+3] = t4.w;
        }
    }

    const float4* xbase = reinterpret_cast<const float4*>(x) + lane;
    const float4* tpb   = reinterpret_cast<const float4*>(tp_ws) + lane;

    float4 xa[8], xb[8];
    #pragma unroll
    for (int m = 0; m < 8; ++m) xa[m] = xbase[m * 64];   // x_0

    float v = 0.f, syn = 0.f, rho = 0.f, tpost = 0.f;

    auto step = [&](int t, const float4 (&xc)[8], float4 (&xn)[8]) {
        // ---- prefetch x_{t+1} (latency hides under this step's compute) ----
        const int tn = (t + 1 < T_STEPS) ? (t + 1) : (T_STEPS - 1);
        const float4* xv = xbase + (size_t)tn * (N_IN / 4);
        #pragma unroll
        for (int m = 0; m < 8; ++m) xn[m] = xv[m * 64];

        // ---- scalar LIF: v_dec uses syn from step t-1's reduce; spike is
        //      decided BEFORE any of this step's dot product ----
        const float v_dec = fmaf(0.1f, syn - v, v);
        const bool refrac = (rho > 0.f);
        const bool spike  = (v_dec > 1.0f) && !refrac;
        v   = (spike || refrac) ? 0.f : v_dec;
        rho = spike ? 5.0f : fmaxf(rho - (refrac ? 1.f : 0.f), 0.f);
        const float zf = spike ? 1.f : 0.f;
        tpost = fmaf(0.05f, zf - tpost, tpost);
        const float c2 = 1e-3f * tpost;
        if (lane == 0) out[t * N_EXC + row] = zf;

        // ---- dot product over PRE-update w (same per-lane fma tree) ----
        float a0 = 0.f, a1 = 0.f, a2 = 0.f, a3 = 0.f;
        #pragma unroll
        for (int m = 0; m < 8; ++m) {
            a0 = fmaf(xc[m].x, w[4*m+0], a0);
            a1 = fmaf(xc[m].y, w[4*m+1], a1);
            a2 = fmaf(xc[m].z, w[4*m+2], a2);
            a3 = fmaf(xc[m].w, w[4*m+3], a3);
        }

        // ---- STDP weight update (wave-uniform branch) ----
        if (spike) {
            const float4* tq4 = tpb + (size_t)t * (N_IN / 4);
            #pragma unroll
            for (int m = 0; m < 8; ++m) {
                float4 tq = tq4[m * 64];
                w[4*m+0] = fmaxf(fmaf(1e-3f, tq.x, fmaf(-c2, xc[m].x, w[4*m+0])), 0.f);
                w[4*m+1] = fmaxf(fmaf(1e-3f, tq.y, fmaf(-c2, xc[m].y, w[4*m+1])), 0.f);
                w[4*m+2] = fmaxf(fmaf(1e-3f, tq.z, fmaf(-c2, xc[m].z, w[4*m+2])), 0.f);
                w[4*m+3] = fmaxf(fmaf(1e-3f, tq.w, fmaf(-c2, xc[m].w, w[4*m+3])), 0.f);
            }
        } else {
            #pragma unroll
            for (int m = 0; m < 8; ++m) {
                w[4*m+0] = fmaxf(fmaf(-c2, xc[m].x, w[4*m+0]), 0.f);
                w[4*m+1] = fmaxf(fmaf(-c2, xc[m].y, w[4*m+1]), 0.f);
                w[4*m+2] = fmaxf(fmaf(-c2, xc[m].z, w[4*m+2]), 0.f);
                w[4*m+3] = fmaxf(fmaf(-c2, xc[m].w, w[4*m+3]), 0.f);
            }
        }

        // ---- reduce LAST: result only needed by step t+1's v_dec ----
        const float inp = wave_sum64((a0 + a1) + (a2 + a3));
        syn = fmaf(0.8f, syn, inp);
    };

    for (int t = 0; t < T_STEPS; t += 2) {
        step(t,     xa, xb);
        step(t + 1, xb, xa);
    }
}

extern "C" void kernel_launch(void* const* d_in, const int* in_sizes, int n_in,
                              void* d_out, int out_size, void* d_ws, size_t ws_size,
                              hipStream_t stream) {
    const float* x  = (const float*)d_in[0];   // exc_currents [128, 2048] f32
    const float* w0 = (const float*)d_in[1];   // w_exc [2048, 2048] f32
    // d_in[2] (w_inh) unused: inhibitory layer does not affect the output
    float* out = (float*)d_out;                // spikes [128, 2048] f32

    float* tp_ws = (float*)d_ws;               // 1 MiB, ws_size is ample
    tp_precompute_kernel<<<N_IN / 256, 256, 0, stream>>>(x, tp_ws);

    dim3 grid(N_EXC / WAVES_PER_BLOCK);        // 512 blocks
    dim3 block(64 * WAVES_PER_BLOCK);          // 256 threads = 4 waves
    snn_exc_kernel<<<grid, block, 0, stream>>>(x, w0, tp_ws, out);
}